// Round 11
// baseline (198.211 us; speedup 1.0000x reference)
//
#include <hip/hip_runtime.h>

// Quantizer via single-product f16 MFMA screening + certified-margin exact
// rescore/rescan.  x: [16,64,32,32] fp32, embed: [64,8192] fp32
//   out[row][c] = embedT[argmax_j (f_row.e_j - ||e_j||^2/2)][c]
//
// R20 = R13 x R19. Ledger after 11 rounds: floor+prep ~52us, qdist ~50us
// (6-MFMA bf16x3; schedule-insensitive across R10/R11/R12), tail ~27us.
// Only >=15us lever left is MFMA count. R13 proved f16 single-product (2
// MFMA/tile) + certified margin M = 1.01*2^-9*||f||*max||e|| + 4e-3 is
// CORRECT (absmax 0) but died on an 89us latency-bound recheck kernel.
// R19 built the cheap replacement: inline wave-cooperative rescan with the
// certified chunk filter pb1[ch] >= b1 - M. This round combines them:
//  - qdist: R13's f16 kernel (2 MFMA/tile, half staging, same swizzle)
//  - prep: + per-row ||f||^2 (inside existing transpose tile) + gn[128]
//  - reduce_rows: 16 lanes/row (1024 blocks, 4 rows/wave): chunk-per-lane
//    merge, quarter-split exact quad rescore for confident rows, inline
//    filtered rescan for flagged rows (~6-9% expected). 3 dispatches.

typedef _Float16 f16;
typedef __attribute__((ext_vector_type(8))) _Float16 f16x8;
typedef __attribute__((ext_vector_type(4))) float f32x4;
typedef unsigned int u32;
typedef unsigned long long u64;

#define N_ROWS  16384
#define E_DIM   64
#define N_EMBED 8192
#define NCHUNK  16
#define COLS_PER_BLOCK (N_EMBED / NCHUNK)   // 512
#define N_ST (COLS_PER_BLOCK / 64)          // 8 stages of 64 codes
#define ROWS_PER_BLOCK 512                  // 4 waves x 128 pixels
#define N_ROWBLK (N_ROWS / ROWS_PER_BLOCK)  // 32
#define NT 8                                // pixel-tiles per wave

// ---- workspace byte offsets (~9 MB total)
#define WS_AH   0u                          // pixel f16 [16384][64] (2 MB)
#define WS_B    (2u << 20)                  // codes f16: 128 groups x 8 KB (1 MB)
#define WS_ET   (3u << 20)                  // embedT fp32 [8192][64] (2 MB)
#define WS_BIAS (5u << 20)                  // -||e_j||^2/2 (32 KB)
#define WS_GN   (WS_BIAS + (32u << 10))     // 128 group maxima of ||e||^2 (512 B)
#define WS_F2   (WS_BIAS + (36u << 10))     // per-row ||f||^2 (64 KB)
#define WS_PB1  (6u << 20)                  // 1 MB
#define WS_PI1  (7u << 20)                  // 1 MB
#define WS_PB2  (8u << 20)                  // 1 MB

__device__ __forceinline__ u32 f32_key(float s) {
    u32 u = __float_as_uint(s);
    return (u & 0x80000000u) ? ~u : (u | 0x80000000u);
}

__device__ __forceinline__ void async16(const void* g, void* l) {
    __builtin_amdgcn_global_load_lds(
        (const __attribute__((address_space(1))) void*)g,
        (__attribute__((address_space(3))) void*)l, 16, 0, 0);
}

// ---- K1: prep. Blocks 0..255: x -> A f16 [row][64] + per-row ||f||^2.
//          Blocks 256..383: embedT fp32, bias, group max||e||^2, swizzled f16 codes.
__global__ __launch_bounds__(256) void prep(
        const float* __restrict__ x, const float* __restrict__ embed, char* ws) {
    __shared__ float tile[64][65];
    f16* Ah = (f16*)(ws + WS_AH);
    float* eT = (float*)(ws + WS_ET);
    float* bias = (float*)(ws + WS_BIAS);
    float* gn = (float*)(ws + WS_GN);
    float* f2g = (float*)(ws + WS_F2);
    const int t = threadIdx.x;
    const int blk = blockIdx.x;

    if (blk < 256) {
        const int b = blk >> 4, p0 = (blk & 15) * 64;
        {
            const int c = t >> 2, seg = (t & 3) * 16;
            const float* src = x + b * 65536 + c * 1024 + p0 + seg;
#pragma unroll
            for (int i = 0; i < 16; ++i) tile[c][seg + i] = src[i];
        }
        __syncthreads();
        const int p = t >> 2, cq = (t & 3) * 16;
        const long row = b * 1024 + p0 + p;
        f16x8 v0, v1;
        float sq = 0.f;
#pragma unroll
        for (int i = 0; i < 16; ++i) {
            float f = tile[cq + i][p];
            sq = fmaf(f, f, sq);
            if (i < 8) v0[i] = (f16)f;
            else       v1[i - 8] = (f16)f;
        }
        // ||f||^2: 4 lanes (cq quarters) of this pixel sum via shfl
        sq += __shfl_xor(sq, 1);
        sq += __shfl_xor(sq, 2);
        if ((t & 3) == 0) f2g[row] = sq;
        *(f16x8*)(Ah + row * 64 + cq) = v0;
        *(f16x8*)(Ah + row * 64 + cq + 8) = v1;
    } else {
        const int g = blk - 256;             // 64-code group
        const int jbase = g * 64;
        f16* Bg = (f16*)(ws + WS_B) + (size_t)g * 4096;   // 64 codes x 64 f16
        {
            const int c = t >> 2, seg = (t & 3) * 16;
            const float* src = embed + c * N_EMBED + jbase + seg;
#pragma unroll
            for (int i = 0; i < 16; ++i) tile[c][seg + i] = src[i];
        }
        __syncthreads();
        if (t < 64) {
            float s = 0.f;
#pragma unroll
            for (int c = 0; c < 64; ++c) { float v = tile[c][t]; s = fmaf(v, v, s); }
            bias[jbase + t] = -0.5f * s;
            // group max of ||e||^2 (wave 0 butterfly), for the certified margin
            float m = s;
#pragma unroll
            for (int off = 1; off < 64; off <<= 1) m = fmaxf(m, __shfl_xor(m, off));
            if (t == 0) gn[g] = m;
        }
        const int jl = t >> 2, cq = (t & 3) * 16;   // channels cq..cq+15
        f16x8 v0, v1;
#pragma unroll
        for (int i = 0; i < 16; ++i) {
            float f = tile[cq + i][jl];
            eT[(long)(jbase + jl) * 64 + cq + i] = f;
            if (i < 8) v0[i] = (f16)f;
            else       v1[i - 8] = (f16)f;
        }
        // granule-XOR swizzle: logical granule k (8 f16) of code jl stored at
        // position k ^ (jl & 7). Staging stays contiguous, LDS reads conflict-free.
        const int k0 = (cq >> 3), sw = jl & 7;
        f16* hi = Bg + jl * 64;
        *(f16x8*)(hi + ((k0 ^ sw) * 8))       = v0;
        *(f16x8*)(hi + (((k0 + 1) ^ sw) * 8)) = v1;
    }
}

// ---- K2: f16 MFMA GEMM + running (quad-max top-2) argmax (R13-proven).
// grid 512 blocks (32 rowblk x 16 chunks), 256 thr, 2 blocks/CU.
__global__ __launch_bounds__(256, 2) void qdist(const char* __restrict__ ws_c, char* __restrict__ ws) {
    __shared__ __align__(16) char smem[2][8192];
    __shared__ __align__(16) float biasLds[512];
    const f16* Ah = (const f16*)(ws_c + WS_AH);
    const char* Bws = ws_c + WS_B;
    const float* biasg = (const float*)(ws_c + WS_BIAS);
    float* pb1 = (float*)(ws + WS_PB1);
    int*   pi1 = (int*)(ws + WS_PI1);
    float* pb2 = (float*)(ws + WS_PB2);

    const int t = threadIdx.x;
    const int wv = t >> 6, lane = t & 63, ln = lane & 15, q = lane >> 4;
    const int rb = blockIdx.x >> 4, chunk = blockIdx.x & 15;
    const int row0 = rb * ROWS_PER_BLOCK;
    const int col0 = chunk * COLS_PER_BLOCK;
    const int g0 = col0 >> 6;               // first 64-code group of this chunk

    // resident pixel fragments (B-operand): 8 pixel-tiles x 2 K-halves
    f16x8 pf[NT][2];
#pragma unroll
    for (int nt = 0; nt < NT; ++nt) {
        long row = row0 + wv * 128 + nt * 16 + ln;
        long base = row * 64 + q * 8;
        pf[nt][0] = *(const f16x8*)(Ah + base);
        pf[nt][1] = *(const f16x8*)(Ah + base + 32);
    }
    asm volatile("" :
        "+v"(pf[0][0]), "+v"(pf[0][1]), "+v"(pf[1][0]), "+v"(pf[1][1]),
        "+v"(pf[2][0]), "+v"(pf[2][1]), "+v"(pf[3][0]), "+v"(pf[3][1]),
        "+v"(pf[4][0]), "+v"(pf[4][1]), "+v"(pf[5][0]), "+v"(pf[5][1]),
        "+v"(pf[6][0]), "+v"(pf[6][1]), "+v"(pf[7][0]), "+v"(pf[7][1]));

    float b1[NT], b2[NT]; int iq[NT];
#pragma unroll
    for (int k = 0; k < NT; ++k) { b1[k] = -3.4e38f; b2[k] = -3.4e38f; iq[k] = 0; }

    // swizzled fragment read offsets: code cl=ct*16+ln; K-granule q^(ln&7)
    const int s7 = ln & 7;
    const int rdbase = ln * 128 + ((q ^ s7) << 4);

    auto issue = [&](int st) {
        const char* src = Bws + (size_t)(g0 + st) * 8192;
        char* dst = smem[st & 1];
#pragma unroll
        for (int s = 0; s < 2; ++s)
            async16(src + s * 4096 + wv * 1024 + lane * 16,
                    dst + s * 4096 + wv * 1024);
    };

    // prologue: stage chunk bias (2 KB) + first B stage; barrier drains both.
    if (t < 128)
        async16((const char*)(biasg + col0) + t * 16,
                (char*)biasLds + (t >> 6) * 1024);
    issue(0);
    for (int st = 0; st < N_ST; ++st) {
        __syncthreads();                 // own staging drained (vmcnt0 before barrier);
        if (st + 1 < N_ST) issue(st + 1);// all waves done reading buf[(st+1)&1]
        const char* buf = smem[st & 1];
        __builtin_amdgcn_s_setprio(1);
#pragma unroll
        for (int ct = 0; ct < 4; ++ct) {
            const int boff = ct * 2048 + rdbase;
            f16x8 ah0 = *(const f16x8*)(buf + boff);
            f16x8 ah1 = *(const f16x8*)(buf + (boff ^ 64));
            f32x4 bv = *(const f32x4*)(biasLds + st * 64 + ct * 16 + q * 4);
            const int jq = col0 + st * 64 + ct * 16 + q * 4;
#pragma unroll
            for (int nt = 0; nt < NT; ++nt) {
                f32x4 acc = __builtin_amdgcn_mfma_f32_16x16x32_f16(ah0, pf[nt][0], bv, 0, 0, 0);
                acc = __builtin_amdgcn_mfma_f32_16x16x32_f16(ah1, pf[nt][1], acc, 0, 0, 0);
                // quad max (4 codes of one pixel)
                float mx = fmaxf(fmaxf(acc[0], acc[1]), fmaxf(acc[2], acc[3]));
                b2[nt] = fmaxf(b2[nt], fminf(b1[nt], mx));
                bool gt = mx > b1[nt];
                b1[nt] = fmaxf(b1[nt], mx);
                iq[nt] = gt ? jq : iq[nt];
            }
        }
        __builtin_amdgcn_s_setprio(0);
    }

    // merge across the 4 quads (same pixel lives in lanes ln, ln+16, ln+32, ln+48)
#pragma unroll
    for (int m = 16; m < 64; m <<= 1) {
#pragma unroll
        for (int nt = 0; nt < NT; ++nt) {
            float o1 = __shfl_xor(b1[nt], m);
            int   oi = __shfl_xor(iq[nt], m);
            float o2 = __shfl_xor(b2[nt], m);
            b2[nt] = fmaxf(fmaxf(fminf(b1[nt], o1), o2), b2[nt]);
            bool take = (o1 > b1[nt]) || (o1 == b1[nt] && oi < iq[nt]);
            if (take) { b1[nt] = o1; iq[nt] = oi; }
        }
    }
    if (q == 0) {
#pragma unroll
        for (int nt = 0; nt < NT; ++nt) {
            int pixel = row0 + wv * 128 + nt * 16 + ln;
            int o = chunk * N_ROWS + pixel;
            pb1[o] = b1[nt];
            pi1[o] = iq[nt];
            pb2[o] = b2[nt];
        }
    }
}

// ---- K3: merge (16 lanes/row) + certified margin + exact quad rescore for
// confident rows + inline wave-cooperative filtered rescan for flagged rows.
// 1024 blocks x 256 thr (16 rows/block, 4 rows/wave). No __syncthreads.
__global__ __launch_bounds__(256) void reduce_rows(const float* __restrict__ x, char* ws,
                                                   float* __restrict__ out) {
    const float* pb1 = (const float*)(ws + WS_PB1);
    const int*   pi1 = (const int*)(ws + WS_PI1);
    const float* pb2 = (const float*)(ws + WS_PB2);
    const float* eT = (const float*)(ws + WS_ET);
    const float* bias = (const float*)(ws + WS_BIAS);
    const float* gn = (const float*)(ws + WS_GN);
    const float* f2g = (const float*)(ws + WS_F2);
    const int t = threadIdx.x;
    const int lane = t & 63, wv = t >> 6;
    const int sub = t & 15;                    // lane within row group = chunk id
    const int rw = (t & 63) >> 4;              // row within wave (0..3)
    const int row = blockIdx.x * 16 + wv * 4 + rw;

    // chunk-per-lane merge (16 chunks over 16 lanes), then butterfly
    float m1 = pb1[sub * N_ROWS + row];
    int   mi = pi1[sub * N_ROWS + row];
    float m2 = pb2[sub * N_ROWS + row];
#pragma unroll
    for (int m = 1; m < 16; m <<= 1) {
        float o1 = __shfl_xor(m1, m);
        int   oi = __shfl_xor(mi, m);
        float o2 = __shfl_xor(m2, m);
        m2 = fmaxf(fmaxf(fminf(m1, o1), o2), m2);
        bool take = (o1 > m1) || (o1 == m1 && oi < mi);
        if (take) { m1 = o1; mi = oi; }
    }

    // certified margin: M = 1.01 * 2^-9 * ||f|| * max||e|| + 4e-3 (R13-validated)
    f32x4 g0v = ((const f32x4*)gn)[sub * 2];
    f32x4 g1v = ((const f32x4*)gn)[sub * 2 + 1];
    float e2 = fmaxf(fmaxf(fmaxf(g0v[0], g0v[1]), fmaxf(g0v[2], g0v[3])),
                     fmaxf(fmaxf(g1v[0], g1v[1]), fmaxf(g1v[2], g1v[3])));
#pragma unroll
    for (int m = 1; m < 16; m <<= 1) e2 = fmaxf(e2, __shfl_xor(e2, m));
    const float f2 = f2g[row];
    const float M = 1.01f * ldexpf(sqrtf(f2) * sqrtf(e2), -9) + 4e-3f;

    const bool flagged = (m1 - m2 < M);        // uniform across row's 16 lanes
    if (!flagged) {
        // exact fp32 rescore of winning quad: code mi+(sub&3), quarter sub>>2
        const float* xb = x + (row >> 10) * 65536 + (row & 1023);
        const int j = mi + (sub & 3);
        const int h = sub >> 2;
        const f32x4* ecd = (const f32x4*)(eT + (size_t)j * 64 + h * 16);
        float s = (h == 0) ? bias[j] : 0.f;
#pragma unroll
        for (int v = 0; v < 4; ++v) {
            f32x4 ev = ecd[v];
            const int c0 = h * 16 + v * 4;
            s = fmaf(xb[(c0 + 0) * 1024], ev[0], s);
            s = fmaf(xb[(c0 + 1) * 1024], ev[1], s);
            s = fmaf(xb[(c0 + 2) * 1024], ev[2], s);
            s = fmaf(xb[(c0 + 3) * 1024], ev[3], s);
        }
        s += __shfl_xor(s, 4);                 // sum quarters (same code)
        s += __shfl_xor(s, 8);
        float best = s; int bj = j;
#pragma unroll
        for (int m = 1; m < 4; m <<= 1) {      // argmax over 4 codes, tie -> low j
            float os = __shfl_xor(best, m);
            int   oj = __shfl_xor(bj, m);
            bool take = (os > best) || (os == best && oj < bj);
            if (take) { best = os; bj = oj; }
        }
        ((f32x4*)(out + (size_t)row * 64))[sub] =
            ((const f32x4*)(eT + (size_t)bj * 64))[sub];
    }

    // ---- rare path: whole wave rescans each flagged row (certified filter) ----
    u64 bal = __ballot(flagged);
    const int wrow0 = blockIdx.x * 16 + wv * 4;
    while (bal) {
        const int b = __ffsll(bal) - 1;
        const int rr = b >> 4;
        bal &= ~(0xFFFFull << (rr * 16));
        const int r = wrow0 + rr;
        const float rb1 = __shfl(m1, rr * 16);
        const float rM  = __shfl(M,  rr * 16);
        const float cutoff = rb1 - rM;         // any true winner's chunk passes

        // broadcast the x row: lane c loads channel c, then shfl to all lanes
        float xv = x[(r >> 10) * 65536 + lane * 1024 + (r & 1023)];
        float xr[64];
#pragma unroll
        for (int c = 0; c < 64; ++c) xr[c] = __shfl(xv, c);

        u64 bestk = 0ull;
        for (int ch = 0; ch < NCHUNK; ++ch) {
            if (pb1[ch * N_ROWS + r] < cutoff) continue;   // wave-uniform branch
#pragma unroll
            for (int k = 0; k < 8; ++k) {
                const int j = ch * 512 + lane * 8 + k;
                const f32x4* ecd = (const f32x4*)(eT + (size_t)j * 64);
                f32x4 a0 = {0.f, 0.f, 0.f, 0.f}, a1 = a0, a2 = a0, a3 = a0;
#pragma unroll
                for (int v = 0; v < 4; ++v) {
                    f32x4 e0 = ecd[v * 4 + 0], e1 = ecd[v * 4 + 1];
                    f32x4 e2v = ecd[v * 4 + 2], e3 = ecd[v * 4 + 3];
#pragma unroll
                    for (int kk = 0; kk < 4; ++kk) {
                        a0[kk] = fmaf(xr[v * 16 + kk],      e0[kk], a0[kk]);
                        a1[kk] = fmaf(xr[v * 16 + 4 + kk],  e1[kk], a1[kk]);
                        a2[kk] = fmaf(xr[v * 16 + 8 + kk],  e2v[kk], a2[kk]);
                        a3[kk] = fmaf(xr[v * 16 + 12 + kk], e3[kk], a3[kk]);
                    }
                }
                f32x4 a01 = a0 + a1, a23 = a2 + a3;
                f32x4 as = a01 + a23;
                float s = bias[j] + ((as[0] + as[1]) + (as[2] + as[3]));
                u64 key = ((u64)f32_key(s) << 32) | (u32)(~(u32)j);
                bestk = (key > bestk) ? key : bestk;
            }
        }
        // wave-wide max (all lanes end with the same key)
#pragma unroll
        for (int m = 1; m < 64; m <<= 1) {
            u64 o = __shfl_xor(bestk, m);
            bestk = (o > bestk) ? o : bestk;
        }
        const int idx = (int)(~(u32)(bestk & 0xffffffffull));
        out[(size_t)r * 64 + lane] = eT[(size_t)idx * 64 + lane];
    }
}

extern "C" void kernel_launch(void* const* d_in, const int* in_sizes, int n_in,
                              void* d_out, int out_size, void* d_ws, size_t ws_size,
                              hipStream_t stream) {
    const float* x     = (const float*)d_in[0];
    const float* embed = (const float*)d_in[1];
    float* out = (float*)d_out;
    char* ws = (char*)d_ws;

    prep<<<384, 256, 0, stream>>>(x, embed, ws);
    qdist<<<N_ROWBLK * NCHUNK, 256, 0, stream>>>(ws, ws);
    reduce_rows<<<N_ROWS / 16, 256, 0, stream>>>(x, ws, out);
}

// Round 12
// 131.860 us; speedup vs baseline: 1.5032x; 1.5032x over previous
//
#include <hip/hip_runtime.h>

// Quantizer via bf16x3-split MFMA GEMM + exact-fp32 recheck of near-ties.
//   x: [16,64,32,32] fp32, embed: [64,8192] fp32
//   out[row][c] = embedT[argmax_j (f_row.e_j - ||e_j||^2/2)][c]
//
// R21: revert to R19 (bf16x3, 2e-3 margin, ~0.1% flags -- the f16 branch is
// closed: R13=89us / R20=116us prove the exact-rescan at f16's certified
// margin costs ~100us regardless of arrangement). New: reduce_rows stages the
// block's x-slice into LDS. A block's 64 rows are 64 CONSECUTIVE pixels of
// one image, so each channel's 64 values are contiguous in x -> coalesced
// 64B-run loads replace the 4KB-stride divergent gathers (1M scattered loads)
// of the quad rescore; rescan reads become LDS broadcasts. 3 dispatches.

typedef __attribute__((ext_vector_type(8))) __bf16 bf16x8;
typedef __attribute__((ext_vector_type(4))) float f32x4;
typedef unsigned int u32;
typedef unsigned long long u64;

union frag_cast { f32x4 f; bf16x8 b; };
__device__ __forceinline__ bf16x8 as_bf16x8(f32x4 v) { frag_cast u; u.f = v; return u.b; }

#define N_ROWS  16384
#define E_DIM   64
#define N_EMBED 8192
#define NCHUNK  16
#define COLS_PER_BLOCK (N_EMBED / NCHUNK)   // 512
#define N_ST (COLS_PER_BLOCK / 64)          // 8 stages of 64 codes
#define ROWS_PER_BLOCK 512                  // 4 waves x 128 pixels
#define N_ROWBLK (N_ROWS / ROWS_PER_BLOCK)  // 32
#define NT 8                                // pixel-tiles per wave
#define MARGIN_THR 2e-3f

// ---- workspace byte offsets (~11.3 MB total)
#define WS_AH   0u              // pixel hi  [16384][64] bf16 (2 MB)
#define WS_AL   (2u << 20)      // pixel lo  (2 MB)
#define WS_B    (4u << 20)      // codes: 128 groups x [hi 64x128B | lo 64x128B] (2 MB)
#define WS_ET   (6u << 20)      // embedT fp32 [8192][64] (2 MB)
#define WS_BIAS (8u << 20)      // -||e_j||^2/2 (32 KB)
#define WS_CNT  (WS_BIAS + (32u << 10))     // (unused scratch)
#define WS_PB1  (WS_CNT + (4u << 10))       // 1 MB
#define WS_PI1  (WS_PB1 + (1u << 20))       // 1 MB
#define WS_PB2  (WS_PI1 + (1u << 20))       // 1 MB

__device__ __forceinline__ u32 f32_key(float s) {
    u32 u = __float_as_uint(s);
    return (u & 0x80000000u) ? ~u : (u | 0x80000000u);
}

__device__ __forceinline__ void async16(const void* g, void* l) {
    __builtin_amdgcn_global_load_lds(
        (const __attribute__((address_space(1))) void*)g,
        (__attribute__((address_space(3))) void*)l, 16, 0, 0);
}

// ---- K1: prep. Blocks 0..255: split x -> A_hi/A_lo [row][64] bf16.
//          Blocks 256..383: embedT fp32, bias, and swizzled interleaved code groups.
__global__ __launch_bounds__(256) void prep(
        const float* __restrict__ x, const float* __restrict__ embed, char* ws) {
    __shared__ float tile[64][65];
    __bf16* Ah = (__bf16*)(ws + WS_AH);
    __bf16* Al = (__bf16*)(ws + WS_AL);
    float*  eT = (float*)(ws + WS_ET);
    float*  bias = (float*)(ws + WS_BIAS);
    const int t = threadIdx.x;
    const int blk = blockIdx.x;

    if (blk < 256) {
        const int b = blk >> 4, p0 = (blk & 15) * 64;
        {
            const int c = t >> 2, seg = (t & 3) * 16;
            const float* src = x + b * 65536 + c * 1024 + p0 + seg;
#pragma unroll
            for (int i = 0; i < 16; ++i) tile[c][seg + i] = src[i];
        }
        __syncthreads();
        const int p = t >> 2, cq = (t & 3) * 16;
        const long row = b * 1024 + p0 + p;
        bf16x8 vh0, vh1, vl0, vl1;
#pragma unroll
        for (int i = 0; i < 16; ++i) {
            float f = tile[cq + i][p];
            __bf16 h = (__bf16)f;
            __bf16 l = (__bf16)(f - (float)h);
            if (i < 8) { vh0[i] = h; vl0[i] = l; }
            else       { vh1[i - 8] = h; vl1[i - 8] = l; }
        }
        *(bf16x8*)(Ah + row * 64 + cq) = vh0;
        *(bf16x8*)(Ah + row * 64 + cq + 8) = vh1;
        *(bf16x8*)(Al + row * 64 + cq) = vl0;
        *(bf16x8*)(Al + row * 64 + cq + 8) = vl1;
    } else {
        const int g = blk - 256;             // 64-code group
        const int jbase = g * 64;
        char* Bg = ws + WS_B + (size_t)g * 16384;
        {
            const int c = t >> 2, seg = (t & 3) * 16;
            const float* src = embed + c * N_EMBED + jbase + seg;
#pragma unroll
            for (int i = 0; i < 16; ++i) tile[c][seg + i] = src[i];
        }
        __syncthreads();
        if (t < 64) {
            float s = 0.f;
#pragma unroll
            for (int c = 0; c < 64; ++c) { float v = tile[c][t]; s = fmaf(v, v, s); }
            bias[jbase + t] = -0.5f * s;
        }
        const int jl = t >> 2, cq = (t & 3) * 16;   // channels cq..cq+15
        bf16x8 vh0, vh1, vl0, vl1;
#pragma unroll
        for (int i = 0; i < 16; ++i) {
            float f = tile[cq + i][jl];
            eT[(long)(jbase + jl) * 64 + cq + i] = f;
            __bf16 h = (__bf16)f;
            __bf16 l = (__bf16)(f - (float)h);
            if (i < 8) { vh0[i] = h; vl0[i] = l; }
            else       { vh1[i - 8] = h; vl1[i - 8] = l; }
        }
        // granule-XOR swizzle: logical granule k (8 bf16) of code jl stored at
        // position k ^ (jl & 7). Keeps staging contiguous, LDS reads conflict-free.
        const int k0 = (cq >> 3), sw = jl & 7;
        __bf16* hi = (__bf16*)Bg + jl * 64;
        __bf16* lo = (__bf16*)(Bg + 8192) + jl * 64;
        *(bf16x8*)(hi + ((k0 ^ sw) * 8))       = vh0;
        *(bf16x8*)(hi + (((k0 + 1) ^ sw) * 8)) = vh1;
        *(bf16x8*)(lo + ((k0 ^ sw) * 8))       = vl0;
        *(bf16x8*)(lo + (((k0 + 1) ^ sw) * 8)) = vl1;
    }
}

// ---- K2: MFMA GEMM + running (quad-max top-2) argmax (proven R9/R15 bytes).
// grid 512 blocks (32 rowblk x 16 chunks), 256 thr, 2 blocks/CU.
__global__ __launch_bounds__(256, 2) void qdist(const char* __restrict__ ws_c, char* __restrict__ ws) {
    __shared__ __align__(16) char smem[2][16384];
    const __bf16* Ah = (const __bf16*)(ws_c + WS_AH);
    const __bf16* Al = (const __bf16*)(ws_c + WS_AL);
    const char* Bws = ws_c + WS_B;
    const float* biasg = (const float*)(ws_c + WS_BIAS);
    float* pb1 = (float*)(ws + WS_PB1);
    int*   pi1 = (int*)(ws + WS_PI1);
    float* pb2 = (float*)(ws + WS_PB2);

    const int t = threadIdx.x;
    const int wv = t >> 6, lane = t & 63, ln = lane & 15, q = lane >> 4;
    const int rb = blockIdx.x >> 4, chunk = blockIdx.x & 15;
    const int row0 = rb * ROWS_PER_BLOCK;
    const int col0 = chunk * COLS_PER_BLOCK;
    const int g0 = col0 >> 6;               // first 64-code group of this chunk

    // resident pixel fragments (B-operand): 8 pixel-tiles x 2 K-halves x {hi,lo}
    f32x4 pfh[NT][2], pfl[NT][2];
#pragma unroll
    for (int nt = 0; nt < NT; ++nt) {
        long row = row0 + wv * 128 + nt * 16 + ln;
        long base = row * 64 + q * 8;
        pfh[nt][0] = *(const f32x4*)(Ah + base);
        pfh[nt][1] = *(const f32x4*)(Ah + base + 32);
        pfl[nt][0] = *(const f32x4*)(Al + base);
        pfl[nt][1] = *(const f32x4*)(Al + base + 32);
    }
    asm volatile("" :
        "+v"(pfh[0][0]), "+v"(pfh[0][1]), "+v"(pfh[1][0]), "+v"(pfh[1][1]),
        "+v"(pfh[2][0]), "+v"(pfh[2][1]), "+v"(pfh[3][0]), "+v"(pfh[3][1]),
        "+v"(pfh[4][0]), "+v"(pfh[4][1]), "+v"(pfh[5][0]), "+v"(pfh[5][1]),
        "+v"(pfh[6][0]), "+v"(pfh[6][1]), "+v"(pfh[7][0]), "+v"(pfh[7][1]));
    asm volatile("" :
        "+v"(pfl[0][0]), "+v"(pfl[0][1]), "+v"(pfl[1][0]), "+v"(pfl[1][1]),
        "+v"(pfl[2][0]), "+v"(pfl[2][1]), "+v"(pfl[3][0]), "+v"(pfl[3][1]),
        "+v"(pfl[4][0]), "+v"(pfl[4][1]), "+v"(pfl[5][0]), "+v"(pfl[5][1]),
        "+v"(pfl[6][0]), "+v"(pfl[6][1]), "+v"(pfl[7][0]), "+v"(pfl[7][1]));

    float b1[NT], b2[NT]; int iq[NT];
#pragma unroll
    for (int k = 0; k < NT; ++k) { b1[k] = -3.4e38f; b2[k] = -3.4e38f; iq[k] = 0; }

    // swizzled fragment read offsets: code cl=ct*16+ln; hi-K0 granule q^(ln&7)
    const int s7 = ln & 7;
    const int rdbase = ln * 128 + ((q ^ s7) << 4);

    auto issue = [&](int st) {
        const char* src = Bws + (size_t)(g0 + st) * 16384;
        char* dst = smem[st & 1];
#pragma unroll
        for (int s = 0; s < 4; ++s)
            async16(src + s * 4096 + wv * 1024 + lane * 16,
                    dst + s * 4096 + wv * 1024);
    };

    issue(0);
    for (int st = 0; st < N_ST; ++st) {
        __syncthreads();                 // own staging drained (vmcnt0 before barrier);
        if (st + 1 < N_ST) issue(st + 1);// all waves done reading buf[(st+1)&1]
        const char* buf = smem[st & 1];
        __builtin_amdgcn_s_setprio(1);
#pragma unroll
        for (int ct = 0; ct < 4; ++ct) {
            const int boff = ct * 2048 + rdbase;
            bf16x8 ah0 = *(const bf16x8*)(buf + boff);
            bf16x8 ah1 = *(const bf16x8*)(buf + (boff ^ 64));
            bf16x8 al0 = *(const bf16x8*)(buf + 8192 + boff);
            bf16x8 al1 = *(const bf16x8*)(buf + 8192 + (boff ^ 64));
            const int cbase = col0 + st * 64 + ct * 16;
            f32x4 bv = *(const f32x4*)(biasg + cbase + q * 4);  // bias for 4 codes
            const int jq = cbase + q * 4;
#pragma unroll
            for (int nt = 0; nt < NT; ++nt) {
                f32x4 acc = __builtin_amdgcn_mfma_f32_16x16x32_bf16(al0, as_bf16x8(pfh[nt][0]), bv, 0, 0, 0);
                acc = __builtin_amdgcn_mfma_f32_16x16x32_bf16(al1, as_bf16x8(pfh[nt][1]), acc, 0, 0, 0);
                acc = __builtin_amdgcn_mfma_f32_16x16x32_bf16(ah0, as_bf16x8(pfl[nt][0]), acc, 0, 0, 0);
                acc = __builtin_amdgcn_mfma_f32_16x16x32_bf16(ah1, as_bf16x8(pfl[nt][1]), acc, 0, 0, 0);
                acc = __builtin_amdgcn_mfma_f32_16x16x32_bf16(ah0, as_bf16x8(pfh[nt][0]), acc, 0, 0, 0);
                acc = __builtin_amdgcn_mfma_f32_16x16x32_bf16(ah1, as_bf16x8(pfh[nt][1]), acc, 0, 0, 0);
                // quad max (4 codes of one pixel)
                float mx = fmaxf(fmaxf(acc[0], acc[1]), fmaxf(acc[2], acc[3]));
                b2[nt] = fmaxf(b2[nt], fminf(b1[nt], mx));
                bool gt = mx > b1[nt];
                b1[nt] = fmaxf(b1[nt], mx);
                iq[nt] = gt ? jq : iq[nt];
            }
        }
        __builtin_amdgcn_s_setprio(0);
    }

    // merge across the 4 quads (same pixel lives in lanes ln, ln+16, ln+32, ln+48)
#pragma unroll
    for (int m = 16; m < 64; m <<= 1) {
#pragma unroll
        for (int nt = 0; nt < NT; ++nt) {
            float o1 = __shfl_xor(b1[nt], m);
            int   oi = __shfl_xor(iq[nt], m);
            float o2 = __shfl_xor(b2[nt], m);
            b2[nt] = fmaxf(fmaxf(fminf(b1[nt], o1), o2), b2[nt]);
            bool take = (o1 > b1[nt]) || (o1 == b1[nt] && oi < iq[nt]);
            if (take) { b1[nt] = o1; iq[nt] = oi; }
        }
    }
    if (q == 0) {
#pragma unroll
        for (int nt = 0; nt < NT; ++nt) {
            int pixel = row0 + wv * 128 + nt * 16 + ln;
            int o = chunk * N_ROWS + pixel;
            pb1[o] = b1[nt];
            pi1[o] = iq[nt];
            pb2[o] = b2[nt];
        }
    }
}

// ---- K3: merge chunks per row (4 lanes/row) + exact quad rescore (x from
// LDS-staged slice, coalesced) + inline wave-cooperative rescan for flags.
// 256 blocks x 256 thr; a block's 64 rows = 64 consecutive pixels of one
// image, so channel c's 64 values are CONTIGUOUS in x.
__global__ __launch_bounds__(256) void reduce_rows(const float* __restrict__ x, char* ws,
                                                   float* __restrict__ out) {
    __shared__ float fl[64][65];                   // [channel][pixel-in-block]
    const float* pb1 = (const float*)(ws + WS_PB1);
    const int*   pi1 = (const int*)(ws + WS_PI1);
    const float* pb2 = (const float*)(ws + WS_PB2);
    const float* eT = (const float*)(ws + WS_ET);
    const float* bias = (const float*)(ws + WS_BIAS);
    const int t = threadIdx.x;
    const int lane = t & 63, wv = t >> 6;
    const int row = (blockIdx.x * 256 + t) >> 2;
    const int sub = t & 3;
    const int rl = (row & 1023) & 63;              // pixel-in-block = wv*16 + (lane>>2)

    // stage the block's x slice: 64 channels x 64 consecutive pixels, coalesced
    {
        const int b = blockIdx.x >> 4;             // image index (64 rows/blk, 1024/img)
        const int p0 = (blockIdx.x * 64) & 1023;   // first pixel of this block
        const int c = t >> 2, seg = sub * 16;
        const float* src = x + b * 65536 + c * 1024 + p0 + seg;
#pragma unroll
        for (int i = 0; i < 16; ++i) fl[c][seg + i] = src[i];
    }
    __syncthreads();

    // per-lane merge over chunks sub*4 .. sub*4+3 (coalesced across the wave)
    float m1 = -3.4e38f, m2 = -3.4e38f; int mi = 0;
#pragma unroll
    for (int k = 0; k < 4; ++k) {
        const int ch = sub * 4 + k;
        float o1 = pb1[ch * N_ROWS + row];
        int   oi = pi1[ch * N_ROWS + row];
        float o2 = pb2[ch * N_ROWS + row];
        m2 = fmaxf(fmaxf(fminf(m1, o1), o2), m2);
        if (o1 > m1 || (o1 == m1 && oi < mi)) { m1 = o1; mi = oi; }
    }
    // merge across the 4 lanes of this row (xor masks 1,2 stay in-group)
#pragma unroll
    for (int m = 1; m < 4; m <<= 1) {
        float o1 = __shfl_xor(m1, m);
        int   oi = __shfl_xor(mi, m);
        float o2 = __shfl_xor(m2, m);
        m2 = fmaxf(fmaxf(fminf(m1, o1), o2), m2);
        bool take = (o1 > m1) || (o1 == m1 && oi < mi);
        if (take) { m1 = o1; mi = oi; }
    }

    const bool flagged = (m1 - m2 < MARGIN_THR);   // uniform across row's 4 lanes
    if (!flagged) {
        // exact fp32 rescore of winning quad: lane sub scores code mi+sub;
        // x channels come from LDS (bank = (c + rl) & 31 -> 2-way, free)
        const int j = mi + sub;
        const f32x4* ecd = (const f32x4*)(eT + (size_t)j * 64);
        float s = bias[j];
#pragma unroll
        for (int v = 0; v < 16; ++v) {
            f32x4 ev = ecd[v];
            s = fmaf(fl[v * 4 + 0][rl], ev[0], s);
            s = fmaf(fl[v * 4 + 1][rl], ev[1], s);
            s = fmaf(fl[v * 4 + 2][rl], ev[2], s);
            s = fmaf(fl[v * 4 + 3][rl], ev[3], s);
        }
        // argmax across the 4 lanes; tie -> lowest j
        float best = s; int bj = j;
#pragma unroll
        for (int m = 1; m < 4; m <<= 1) {
            float os = __shfl_xor(best, m);
            int   oj = __shfl_xor(bj, m);
            bool take = (os > best) || (os == best && oj < bj);
            if (take) { best = os; bj = oj; }
        }
        // cooperative row write: 4 lanes x 4 f32x4
        const f32x4* src = (const f32x4*)(eT + (size_t)bj * 64);
        f32x4* dst = (f32x4*)(out + (size_t)row * 64);
#pragma unroll
        for (int v = 0; v < 4; ++v) dst[v * 4 + sub] = src[v * 4 + sub];
    }

    // ---- rare path: whole wave rescans each flagged row of its 16 rows ----
    u64 bal = __ballot(flagged);
    const int wrow0 = blockIdx.x * 64 + wv * 16;     // first row of this wave
    while (bal) {
        const int b = __ffsll(bal) - 1;
        const int rw = b >> 2;
        bal &= ~(0xFull << (rw * 4));
        const int r = wrow0 + rw;
        const int rlr = wv * 16 + rw;                // pixel-in-block of row r
        const float rb1 = __shfl(m1, rw * 4);        // row's merged approx max
        const float cutoff = rb1 - 2.0f * MARGIN_THR;

        // x row from LDS (same address across lanes -> broadcast, conflict-free)
        float xr[64];
#pragma unroll
        for (int c = 0; c < 64; ++c) xr[c] = fl[c][rlr];

        u64 bestk = 0ull;
        for (int ch = 0; ch < NCHUNK; ++ch) {
            // any code that could truly win has approx >= rb1 - 2*eps, and its
            // chunk max pb1 >= that; cutoff uses 2*THR (2x slack vs the same
            // eps<=THR/2 assumption the margin test relies on).
            if (pb1[ch * N_ROWS + r] < cutoff) continue;   // wave-uniform branch
#pragma unroll
            for (int k = 0; k < 8; ++k) {
                const int j = ch * 512 + lane * 8 + k;
                const f32x4* ecd = (const f32x4*)(eT + (size_t)j * 64);
                f32x4 a0 = {0.f, 0.f, 0.f, 0.f}, a1 = a0, a2 = a0, a3 = a0;
#pragma unroll
                for (int v = 0; v < 4; ++v) {
                    f32x4 e0 = ecd[v * 4 + 0], e1 = ecd[v * 4 + 1];
                    f32x4 e2 = ecd[v * 4 + 2], e3 = ecd[v * 4 + 3];
#pragma unroll
                    for (int kk = 0; kk < 4; ++kk) {
                        a0[kk] = fmaf(xr[v * 16 + kk],      e0[kk], a0[kk]);
                        a1[kk] = fmaf(xr[v * 16 + 4 + kk],  e1[kk], a1[kk]);
                        a2[kk] = fmaf(xr[v * 16 + 8 + kk],  e2[kk], a2[kk]);
                        a3[kk] = fmaf(xr[v * 16 + 12 + kk], e3[kk], a3[kk]);
                    }
                }
                f32x4 a01 = a0 + a1, a23 = a2 + a3;
                f32x4 as = a01 + a23;
                float s = bias[j] + ((as[0] + as[1]) + (as[2] + as[3]));
                u64 key = ((u64)f32_key(s) << 32) | (u32)(~(u32)j);
                bestk = (key > bestk) ? key : bestk;
            }
        }
        // wave-wide max (all lanes end with the same key)
#pragma unroll
        for (int m = 1; m < 64; m <<= 1) {
            u64 o = __shfl_xor(bestk, m);
            bestk = (o > bestk) ? o : bestk;
        }
        const int idx = (int)(~(u32)(bestk & 0xffffffffull));
        out[(size_t)r * 64 + lane] = eT[(size_t)idx * 64 + lane];
    }
}

extern "C" void kernel_launch(void* const* d_in, const int* in_sizes, int n_in,
                              void* d_out, int out_size, void* d_ws, size_t ws_size,
                              hipStream_t stream) {
    const float* x     = (const float*)d_in[0];
    const float* embed = (const float*)d_in[1];
    float* out = (float*)d_out;
    char* ws = (char*)d_ws;

    prep<<<384, 256, 0, stream>>>(x, embed, ws);
    qdist<<<N_ROWBLK * NCHUNK, 256, 0, stream>>>(ws, ws);
    reduce_rows<<<256, 256, 0, stream>>>(x, ws, out);
}

// Round 13
// 129.333 us; speedup vs baseline: 1.5326x; 1.0195x over previous
//
#include <hip/hip_runtime.h>

// Quantizer via bf16x3-split MFMA GEMM + exact-fp32 recheck of near-ties.
//   x: [16,64,32,32] fp32, embed: [64,8192] fp32
//   out[row][c] = embedT[argmax_j (f_row.e_j - ||e_j||^2/2)][c]
//
// R22: CLEAN occupancy retest of qdist. R11's "occupancy doesn't help" was
// confounded: __launch_bounds__(256,4) made the compiler allocate 64 VGPRs
// (< the 64-reg pf arrays) -> spill (WRITE_SIZE 18MB signature). Redo with
// NT=4 / grid 1024 / __launch_bounds__(256,3): VGPR cap ~170 -> compiler
// allocates its natural ~116, which lands in the (64,128] quantization bin
// = 4 waves/SIMD (2x occupancy, no spill). Falsifiable: VGPR~116 + WRITE~3MB
// confirm clean; then MfmaUtil must move if wave-phase starvation was real.
// prep/reduce_rows byte-identical to R21 (tail is insensitive, 129-132 x5).

typedef __attribute__((ext_vector_type(8))) __bf16 bf16x8;
typedef __attribute__((ext_vector_type(4))) float f32x4;
typedef unsigned int u32;
typedef unsigned long long u64;

union frag_cast { f32x4 f; bf16x8 b; };
__device__ __forceinline__ bf16x8 as_bf16x8(f32x4 v) { frag_cast u; u.f = v; return u.b; }

#define N_ROWS  16384
#define E_DIM   64
#define N_EMBED 8192
#define NCHUNK  16
#define COLS_PER_BLOCK (N_EMBED / NCHUNK)   // 512
#define N_ST (COLS_PER_BLOCK / 64)          // 8 stages of 64 codes
#define ROWS_PER_BLOCK 256                  // 4 waves x 64 pixels
#define N_ROWBLK (N_ROWS / ROWS_PER_BLOCK)  // 64
#define NT 4                                // pixel-tiles per wave
#define MARGIN_THR 2e-3f

// ---- workspace byte offsets (~11.3 MB total)
#define WS_AH   0u              // pixel hi  [16384][64] bf16 (2 MB)
#define WS_AL   (2u << 20)      // pixel lo  (2 MB)
#define WS_B    (4u << 20)      // codes: 128 groups x [hi 64x128B | lo 64x128B] (2 MB)
#define WS_ET   (6u << 20)      // embedT fp32 [8192][64] (2 MB)
#define WS_BIAS (8u << 20)      // -||e_j||^2/2 (32 KB)
#define WS_CNT  (WS_BIAS + (32u << 10))     // (unused scratch)
#define WS_PB1  (WS_CNT + (4u << 10))       // 1 MB
#define WS_PI1  (WS_PB1 + (1u << 20))       // 1 MB
#define WS_PB2  (WS_PI1 + (1u << 20))       // 1 MB

__device__ __forceinline__ u32 f32_key(float s) {
    u32 u = __float_as_uint(s);
    return (u & 0x80000000u) ? ~u : (u | 0x80000000u);
}

__device__ __forceinline__ void async16(const void* g, void* l) {
    __builtin_amdgcn_global_load_lds(
        (const __attribute__((address_space(1))) void*)g,
        (__attribute__((address_space(3))) void*)l, 16, 0, 0);
}

// ---- K1: prep. Blocks 0..255: split x -> A_hi/A_lo [row][64] bf16.
//          Blocks 256..383: embedT fp32, bias, and swizzled interleaved code groups.
__global__ __launch_bounds__(256) void prep(
        const float* __restrict__ x, const float* __restrict__ embed, char* ws) {
    __shared__ float tile[64][65];
    __bf16* Ah = (__bf16*)(ws + WS_AH);
    __bf16* Al = (__bf16*)(ws + WS_AL);
    float*  eT = (float*)(ws + WS_ET);
    float*  bias = (float*)(ws + WS_BIAS);
    const int t = threadIdx.x;
    const int blk = blockIdx.x;

    if (blk < 256) {
        const int b = blk >> 4, p0 = (blk & 15) * 64;
        {
            const int c = t >> 2, seg = (t & 3) * 16;
            const float* src = x + b * 65536 + c * 1024 + p0 + seg;
#pragma unroll
            for (int i = 0; i < 16; ++i) tile[c][seg + i] = src[i];
        }
        __syncthreads();
        const int p = t >> 2, cq = (t & 3) * 16;
        const long row = b * 1024 + p0 + p;
        bf16x8 vh0, vh1, vl0, vl1;
#pragma unroll
        for (int i = 0; i < 16; ++i) {
            float f = tile[cq + i][p];
            __bf16 h = (__bf16)f;
            __bf16 l = (__bf16)(f - (float)h);
            if (i < 8) { vh0[i] = h; vl0[i] = l; }
            else       { vh1[i - 8] = h; vl1[i - 8] = l; }
        }
        *(bf16x8*)(Ah + row * 64 + cq) = vh0;
        *(bf16x8*)(Ah + row * 64 + cq + 8) = vh1;
        *(bf16x8*)(Al + row * 64 + cq) = vl0;
        *(bf16x8*)(Al + row * 64 + cq + 8) = vl1;
    } else {
        const int g = blk - 256;             // 64-code group
        const int jbase = g * 64;
        char* Bg = ws + WS_B + (size_t)g * 16384;
        {
            const int c = t >> 2, seg = (t & 3) * 16;
            const float* src = embed + c * N_EMBED + jbase + seg;
#pragma unroll
            for (int i = 0; i < 16; ++i) tile[c][seg + i] = src[i];
        }
        __syncthreads();
        if (t < 64) {
            float s = 0.f;
#pragma unroll
            for (int c = 0; c < 64; ++c) { float v = tile[c][t]; s = fmaf(v, v, s); }
            bias[jbase + t] = -0.5f * s;
        }
        const int jl = t >> 2, cq = (t & 3) * 16;   // channels cq..cq+15
        bf16x8 vh0, vh1, vl0, vl1;
#pragma unroll
        for (int i = 0; i < 16; ++i) {
            float f = tile[cq + i][jl];
            eT[(long)(jbase + jl) * 64 + cq + i] = f;
            __bf16 h = (__bf16)f;
            __bf16 l = (__bf16)(f - (float)h);
            if (i < 8) { vh0[i] = h; vl0[i] = l; }
            else       { vh1[i - 8] = h; vl1[i - 8] = l; }
        }
        // granule-XOR swizzle: logical granule k (8 bf16) of code jl stored at
        // position k ^ (jl & 7). Keeps staging contiguous, LDS reads conflict-free.
        const int k0 = (cq >> 3), sw = jl & 7;
        __bf16* hi = (__bf16*)Bg + jl * 64;
        __bf16* lo = (__bf16*)(Bg + 8192) + jl * 64;
        *(bf16x8*)(hi + ((k0 ^ sw) * 8))       = vh0;
        *(bf16x8*)(hi + (((k0 + 1) ^ sw) * 8)) = vh1;
        *(bf16x8*)(lo + ((k0 ^ sw) * 8))       = vl0;
        *(bf16x8*)(lo + (((k0 + 1) ^ sw) * 8)) = vl1;
    }
}

// ---- K2: MFMA GEMM + running (quad-max top-2) argmax.
// grid 1024 blocks (64 rowblk x 16 chunks), 256 thr, target 4 blocks/CU.
// launch_bounds(256,3): VGPR cap ~170 -> natural ~116 alloc (no R11 spill),
// 116 <= 128 quantization bin -> 4 waves/SIMD.
__global__ __launch_bounds__(256, 3) void qdist(const char* __restrict__ ws_c, char* __restrict__ ws) {
    __shared__ __align__(16) char smem[2][16384];
    const __bf16* Ah = (const __bf16*)(ws_c + WS_AH);
    const __bf16* Al = (const __bf16*)(ws_c + WS_AL);
    const char* Bws = ws_c + WS_B;
    const float* biasg = (const float*)(ws_c + WS_BIAS);
    float* pb1 = (float*)(ws + WS_PB1);
    int*   pi1 = (int*)(ws + WS_PI1);
    float* pb2 = (float*)(ws + WS_PB2);

    const int t = threadIdx.x;
    const int wv = t >> 6, lane = t & 63, ln = lane & 15, q = lane >> 4;
    const int rb = blockIdx.x >> 4, chunk = blockIdx.x & 15;
    const int row0 = rb * ROWS_PER_BLOCK;
    const int col0 = chunk * COLS_PER_BLOCK;
    const int g0 = col0 >> 6;               // first 64-code group of this chunk

    // resident pixel fragments (B-operand): 4 pixel-tiles x 2 K-halves x {hi,lo}
    f32x4 pfh[NT][2], pfl[NT][2];
#pragma unroll
    for (int nt = 0; nt < NT; ++nt) {
        long row = row0 + wv * 64 + nt * 16 + ln;
        long base = row * 64 + q * 8;
        pfh[nt][0] = *(const f32x4*)(Ah + base);
        pfh[nt][1] = *(const f32x4*)(Ah + base + 32);
        pfl[nt][0] = *(const f32x4*)(Al + base);
        pfl[nt][1] = *(const f32x4*)(Al + base + 32);
    }
    asm volatile("" :
        "+v"(pfh[0][0]), "+v"(pfh[0][1]), "+v"(pfh[1][0]), "+v"(pfh[1][1]),
        "+v"(pfh[2][0]), "+v"(pfh[2][1]), "+v"(pfh[3][0]), "+v"(pfh[3][1]),
        "+v"(pfl[0][0]), "+v"(pfl[0][1]), "+v"(pfl[1][0]), "+v"(pfl[1][1]),
        "+v"(pfl[2][0]), "+v"(pfl[2][1]), "+v"(pfl[3][0]), "+v"(pfl[3][1]));

    float b1[NT], b2[NT]; int iq[NT];
#pragma unroll
    for (int k = 0; k < NT; ++k) { b1[k] = -3.4e38f; b2[k] = -3.4e38f; iq[k] = 0; }

    // swizzled fragment read offsets: code cl=ct*16+ln; hi-K0 granule q^(ln&7)
    const int s7 = ln & 7;
    const int rdbase = ln * 128 + ((q ^ s7) << 4);

    auto issue = [&](int st) {
        const char* src = Bws + (size_t)(g0 + st) * 16384;
        char* dst = smem[st & 1];
#pragma unroll
        for (int s = 0; s < 4; ++s)
            async16(src + s * 4096 + wv * 1024 + lane * 16,
                    dst + s * 4096 + wv * 1024);
    };

    issue(0);
    for (int st = 0; st < N_ST; ++st) {
        __syncthreads();                 // own staging drained (vmcnt0 before barrier);
        if (st + 1 < N_ST) issue(st + 1);// all waves done reading buf[(st+1)&1]
        const char* buf = smem[st & 1];
        __builtin_amdgcn_s_setprio(1);
#pragma unroll
        for (int ct = 0; ct < 4; ++ct) {
            const int boff = ct * 2048 + rdbase;
            bf16x8 ah0 = *(const bf16x8*)(buf + boff);
            bf16x8 ah1 = *(const bf16x8*)(buf + (boff ^ 64));
            bf16x8 al0 = *(const bf16x8*)(buf + 8192 + boff);
            bf16x8 al1 = *(const bf16x8*)(buf + 8192 + (boff ^ 64));
            const int cbase = col0 + st * 64 + ct * 16;
            f32x4 bv = *(const f32x4*)(biasg + cbase + q * 4);  // bias for 4 codes
            const int jq = cbase + q * 4;
#pragma unroll
            for (int nt = 0; nt < NT; ++nt) {
                f32x4 acc = __builtin_amdgcn_mfma_f32_16x16x32_bf16(al0, as_bf16x8(pfh[nt][0]), bv, 0, 0, 0);
                acc = __builtin_amdgcn_mfma_f32_16x16x32_bf16(al1, as_bf16x8(pfh[nt][1]), acc, 0, 0, 0);
                acc = __builtin_amdgcn_mfma_f32_16x16x32_bf16(ah0, as_bf16x8(pfl[nt][0]), acc, 0, 0, 0);
                acc = __builtin_amdgcn_mfma_f32_16x16x32_bf16(ah1, as_bf16x8(pfl[nt][1]), acc, 0, 0, 0);
                acc = __builtin_amdgcn_mfma_f32_16x16x32_bf16(ah0, as_bf16x8(pfh[nt][0]), acc, 0, 0, 0);
                acc = __builtin_amdgcn_mfma_f32_16x16x32_bf16(ah1, as_bf16x8(pfh[nt][1]), acc, 0, 0, 0);
                // quad max (4 codes of one pixel)
                float mx = fmaxf(fmaxf(acc[0], acc[1]), fmaxf(acc[2], acc[3]));
                b2[nt] = fmaxf(b2[nt], fminf(b1[nt], mx));
                bool gt = mx > b1[nt];
                b1[nt] = fmaxf(b1[nt], mx);
                iq[nt] = gt ? jq : iq[nt];
            }
        }
        __builtin_amdgcn_s_setprio(0);
    }

    // merge across the 4 quads (same pixel lives in lanes ln, ln+16, ln+32, ln+48)
#pragma unroll
    for (int m = 16; m < 64; m <<= 1) {
#pragma unroll
        for (int nt = 0; nt < NT; ++nt) {
            float o1 = __shfl_xor(b1[nt], m);
            int   oi = __shfl_xor(iq[nt], m);
            float o2 = __shfl_xor(b2[nt], m);
            b2[nt] = fmaxf(fmaxf(fminf(b1[nt], o1), o2), b2[nt]);
            bool take = (o1 > b1[nt]) || (o1 == b1[nt] && oi < iq[nt]);
            if (take) { b1[nt] = o1; iq[nt] = oi; }
        }
    }
    if (q == 0) {
#pragma unroll
        for (int nt = 0; nt < NT; ++nt) {
            int pixel = row0 + wv * 64 + nt * 16 + ln;
            int o = chunk * N_ROWS + pixel;
            pb1[o] = b1[nt];
            pi1[o] = iq[nt];
            pb2[o] = b2[nt];
        }
    }
}

// ---- K3: merge chunks per row (4 lanes/row) + exact quad rescore (x from
// LDS-staged slice, coalesced) + inline wave-cooperative rescan for flags.
// 256 blocks x 256 thr; a block's 64 rows = 64 consecutive pixels of one
// image, so channel c's 64 values are CONTIGUOUS in x.
__global__ __launch_bounds__(256) void reduce_rows(const float* __restrict__ x, char* ws,
                                                   float* __restrict__ out) {
    __shared__ float fl[64][65];                   // [channel][pixel-in-block]
    const float* pb1 = (const float*)(ws + WS_PB1);
    const int*   pi1 = (const int*)(ws + WS_PI1);
    const float* pb2 = (const float*)(ws + WS_PB2);
    const float* eT = (const float*)(ws + WS_ET);
    const float* bias = (const float*)(ws + WS_BIAS);
    const int t = threadIdx.x;
    const int lane = t & 63, wv = t >> 6;
    const int row = (blockIdx.x * 256 + t) >> 2;
    const int sub = t & 3;
    const int rl = (row & 1023) & 63;              // pixel-in-block = wv*16 + (lane>>2)

    // stage the block's x slice: 64 channels x 64 consecutive pixels, coalesced
    {
        const int b = blockIdx.x >> 4;             // image index (64 rows/blk, 1024/img)
        const int p0 = (blockIdx.x * 64) & 1023;   // first pixel of this block
        const int c = t >> 2, seg = sub * 16;
        const float* src = x + b * 65536 + c * 1024 + p0 + seg;
#pragma unroll
        for (int i = 0; i < 16; ++i) fl[c][seg + i] = src[i];
    }
    __syncthreads();

    // per-lane merge over chunks sub*4 .. sub*4+3 (coalesced across the wave)
    float m1 = -3.4e38f, m2 = -3.4e38f; int mi = 0;
#pragma unroll
    for (int k = 0; k < 4; ++k) {
        const int ch = sub * 4 + k;
        float o1 = pb1[ch * N_ROWS + row];
        int   oi = pi1[ch * N_ROWS + row];
        float o2 = pb2[ch * N_ROWS + row];
        m2 = fmaxf(fmaxf(fminf(m1, o1), o2), m2);
        if (o1 > m1 || (o1 == m1 && oi < mi)) { m1 = o1; mi = oi; }
    }
    // merge across the 4 lanes of this row (xor masks 1,2 stay in-group)
#pragma unroll
    for (int m = 1; m < 4; m <<= 1) {
        float o1 = __shfl_xor(m1, m);
        int   oi = __shfl_xor(mi, m);
        float o2 = __shfl_xor(m2, m);
        m2 = fmaxf(fmaxf(fminf(m1, o1), o2), m2);
        bool take = (o1 > m1) || (o1 == m1 && oi < mi);
        if (take) { m1 = o1; mi = oi; }
    }

    const bool flagged = (m1 - m2 < MARGIN_THR);   // uniform across row's 4 lanes
    if (!flagged) {
        // exact fp32 rescore of winning quad: lane sub scores code mi+sub;
        // x channels come from LDS (bank = (c + rl) & 31 -> 2-way, free)
        const int j = mi + sub;
        const f32x4* ecd = (const f32x4*)(eT + (size_t)j * 64);
        float s = bias[j];
#pragma unroll
        for (int v = 0; v < 16; ++v) {
            f32x4 ev = ecd[v];
            s = fmaf(fl[v * 4 + 0][rl], ev[0], s);
            s = fmaf(fl[v * 4 + 1][rl], ev[1], s);
            s = fmaf(fl[v * 4 + 2][rl], ev[2], s);
            s = fmaf(fl[v * 4 + 3][rl], ev[3], s);
        }
        // argmax across the 4 lanes; tie -> lowest j
        float best = s; int bj = j;
#pragma unroll
        for (int m = 1; m < 4; m <<= 1) {
            float os = __shfl_xor(best, m);
            int   oj = __shfl_xor(bj, m);
            bool take = (os > best) || (os == best && oj < bj);
            if (take) { best = os; bj = oj; }
        }
        // cooperative row write: 4 lanes x 4 f32x4
        const f32x4* src = (const f32x4*)(eT + (size_t)bj * 64);
        f32x4* dst = (f32x4*)(out + (size_t)row * 64);
#pragma unroll
        for (int v = 0; v < 4; ++v) dst[v * 4 + sub] = src[v * 4 + sub];
    }

    // ---- rare path: whole wave rescans each flagged row of its 16 rows ----
    u64 bal = __ballot(flagged);
    const int wrow0 = blockIdx.x * 64 + wv * 16;     // first row of this wave
    while (bal) {
        const int b = __ffsll(bal) - 1;
        const int rw = b >> 2;
        bal &= ~(0xFull << (rw * 4));
        const int r = wrow0 + rw;
        const int rlr = wv * 16 + rw;                // pixel-in-block of row r
        const float rb1 = __shfl(m1, rw * 4);        // row's merged approx max
        const float cutoff = rb1 - 2.0f * MARGIN_THR;

        // x row from LDS (same address across lanes -> broadcast, conflict-free)
        float xr[64];
#pragma unroll
        for (int c = 0; c < 64; ++c) xr[c] = fl[c][rlr];

        u64 bestk = 0ull;
        for (int ch = 0; ch < NCHUNK; ++ch) {
            // any code that could truly win has approx >= rb1 - 2*eps, and its
            // chunk max pb1 >= that; cutoff uses 2*THR (2x slack vs the same
            // eps<=THR/2 assumption the margin test relies on).
            if (pb1[ch * N_ROWS + r] < cutoff) continue;   // wave-uniform branch
#pragma unroll
            for (int k = 0; k < 8; ++k) {
                const int j = ch * 512 + lane * 8 + k;
                const f32x4* ecd = (const f32x4*)(eT + (size_t)j * 64);
                f32x4 a0 = {0.f, 0.f, 0.f, 0.f}, a1 = a0, a2 = a0, a3 = a0;
#pragma unroll
                for (int v = 0; v < 4; ++v) {
                    f32x4 e0 = ecd[v * 4 + 0], e1 = ecd[v * 4 + 1];
                    f32x4 e2 = ecd[v * 4 + 2], e3 = ecd[v * 4 + 3];
#pragma unroll
                    for (int kk = 0; kk < 4; ++kk) {
                        a0[kk] = fmaf(xr[v * 16 + kk],      e0[kk], a0[kk]);
                        a1[kk] = fmaf(xr[v * 16 + 4 + kk],  e1[kk], a1[kk]);
                        a2[kk] = fmaf(xr[v * 16 + 8 + kk],  e2[kk], a2[kk]);
                        a3[kk] = fmaf(xr[v * 16 + 12 + kk], e3[kk], a3[kk]);
                    }
                }
                f32x4 a01 = a0 + a1, a23 = a2 + a3;
                f32x4 as = a01 + a23;
                float s = bias[j] + ((as[0] + as[1]) + (as[2] + as[3]));
                u64 key = ((u64)f32_key(s) << 32) | (u32)(~(u32)j);
                bestk = (key > bestk) ? key : bestk;
            }
        }
        // wave-wide max (all lanes end with the same key)
#pragma unroll
        for (int m = 1; m < 64; m <<= 1) {
            u64 o = __shfl_xor(bestk, m);
            bestk = (o > bestk) ? o : bestk;
        }
        const int idx = (int)(~(u32)(bestk & 0xffffffffull));
        out[(size_t)r * 64 + lane] = eT[(size_t)idx * 64 + lane];
    }
}

extern "C" void kernel_launch(void* const* d_in, const int* in_sizes, int n_in,
                              void* d_out, int out_size, void* d_ws, size_t ws_size,
                              hipStream_t stream) {
    const float* x     = (const float*)d_in[0];
    const float* embed = (const float*)d_in[1];
    float* out = (float*)d_out;
    char* ws = (char*)d_ws;

    prep<<<384, 256, 0, stream>>>(x, embed, ws);
    qdist<<<N_ROWBLK * NCHUNK, 256, 0, stream>>>(ws, ws);
    reduce_rows<<<256, 256, 0, stream>>>(x, ws, out);
}